// Round 6
// baseline (191.974 us; speedup 1.0000x reference)
//
#include <hip/hip_runtime.h>

// Chamfer distance, deterministic (atomicMin on uint keys is order-independent).
// pts = img_render_points[0]      : 4096 x 2 f32 (slice 0)
// refs = ref_catheter_skeleton[1] : 32768 x 2 f32 (last slice; flip is neutral)
//
// ||p-r||^2 = ||p||^2 + (||r||^2 - 2 p.r)
// LDS staged record: (-2*r.x, -2*r.y, ||r||^2, 0) -> one broadcast ds_read_b128.
// 16 own points/thread: 16 pairs per ds_read; inner = 2 FMA/pair + v_min3 amortized.
// Cross-slice combine via atomicMin on nonneg-float uint bitcast (monotone).

constexpr int N_PTS = 4096;
constexpr int M_REF = 32768;
constexpr int P_OWN = 16;   // own points per thread
constexpr int S_STG = 128;  // staged points per block (slice)
constexpr int N_MIN = N_PTS + M_REF;          // 36864 min slots
constexpr unsigned int INIT_BITS = 0x7F7F7F7Fu;  // ~3.39e38 as float

// ---------------- Kernel 0: init min buffer (uint4 fills) ------------------
__global__ __launch_bounds__(256) void chamfer_init_kernel(uint4* __restrict__ minbuf)
{
    const int i = blockIdx.x * 256 + threadIdx.x;   // 36 blocks x 256 = 9216 uint4
    minbuf[i] = make_uint4(INIT_BITS, INIT_BITS, INIT_BITS, INIT_BITS);
}

// ---------------- Kernel 1: pairwise mins via atomicMin --------------------
// Grid: 512 blocks x 256 threads.
//  rows (b < 256):  own = all 4096 pts (256 thr x 16), staged = refs slice b (128)
//  cols (b >= 256): own = refs chunk (bb&7)*4096 + ..., staged = pts slice (bb>>3)
__global__ __launch_bounds__(256) void chamfer_main_kernel(
    const float2* __restrict__ pts, const float2* __restrict__ refs,
    unsigned int* __restrict__ rowmin,   // [N_PTS]
    unsigned int* __restrict__ colmin)   // [M_REF]
{
    __shared__ float4 sh[S_STG];   // 2 KB
    const int tid = threadIdx.x, b = blockIdx.x;

    const float2* own; const float2* oth; unsigned int* omin;
    int ownBase, sbase;
    if (b < 256) {                        // rows: own = pts, staged = refs
        own = pts;  oth = refs;
        ownBase = tid * P_OWN;            // covers all 4096 pts
        sbase   = b * S_STG;
        omin    = rowmin + ownBase;
    } else {                              // cols: own = refs, staged = pts
        const int bb = b - 256;
        own = refs; oth = pts;
        ownBase = (bb & 7) * 4096 + tid * P_OWN;
        sbase   = (bb >> 3) * S_STG;
        omin    = colmin + ownBase;
    }

    // Stage S_STG records (threads 0..127), computing (-2x,-2y,n2) on the fly.
    if (tid < S_STG) {
        const float2 r = oth[sbase + tid];
        sh[tid] = make_float4(-2.f * r.x, -2.f * r.y, fmaf(r.x, r.x, r.y * r.y), 0.f);
    }

    // Load 16 own points (8 x float4 = 128 B contiguous per thread).
    float px[P_OWN], py[P_OWN], n2[P_OWN], mn[P_OWN];
    {
        const float4* o4 = (const float4*)(own + ownBase);
        #pragma unroll
        for (int q = 0; q < P_OWN / 2; ++q) {
            const float4 o = o4[q];
            px[2 * q]     = o.x; py[2 * q]     = o.y;
            px[2 * q + 1] = o.z; py[2 * q + 1] = o.w;
        }
        #pragma unroll
        for (int k = 0; k < P_OWN; ++k) {
            n2[k] = fmaf(px[k], px[k], py[k] * py[k]);
            mn[k] = 3.0e38f;
        }
    }
    __syncthreads();

    for (int j = 0; j < S_STG; j += 4) {   // broadcast ds_read_b128 x4 per iter
        const float4 r0 = sh[j];
        const float4 r1 = sh[j + 1];
        const float4 r2 = sh[j + 2];
        const float4 r3 = sh[j + 3];
        #pragma unroll
        for (int k = 0; k < P_OWN; ++k) {
            const float d0 = fmaf(px[k], r0.x, fmaf(py[k], r0.y, r0.z));
            const float d1 = fmaf(px[k], r1.x, fmaf(py[k], r1.y, r1.z));
            const float d2 = fmaf(px[k], r2.x, fmaf(py[k], r2.y, r2.z));
            const float d3 = fmaf(px[k], r3.x, fmaf(py[k], r3.y, r3.z));
            mn[k] = fminf(fminf(mn[k], d0), d1);   // v_min3_f32
            mn[k] = fminf(fminf(mn[k], d2), d3);   // v_min3_f32
        }
    }

    // Full squared distance = mn + ||own||^2 >= 0 (clamp fp slop), then
    // uint bitcast is order-preserving -> atomicMin is exact and deterministic.
    #pragma unroll
    for (int k = 0; k < P_OWN; ++k) {
        const float sq = fmaxf(mn[k] + n2[k], 0.f);
        atomicMin(&omin[k], __float_as_uint(sq));
    }
}

// ---------------- Kernel 2: sqrt + per-block sums --------------------------
// 36 blocks x 256 threads, 4 values/thread (uint4), minbuf is L2-hot.
__global__ __launch_bounds__(256) void chamfer_sqrtsum_kernel(
    const uint4* __restrict__ minbuf, float* __restrict__ blocksum)
{
    __shared__ float ssum[4];
    const int tid = threadIdx.x, b = blockIdx.x;
    const uint4 v = minbuf[b * 256 + tid];
    float d = sqrtf(fmaxf(__uint_as_float(v.x), 1e-12f))
            + sqrtf(fmaxf(__uint_as_float(v.y), 1e-12f))
            + sqrtf(fmaxf(__uint_as_float(v.z), 1e-12f))
            + sqrtf(fmaxf(__uint_as_float(v.w), 1e-12f));
    #pragma unroll
    for (int off = 32; off > 0; off >>= 1) d += __shfl_down(d, off, 64);
    const int lane = tid & 63, wave = tid >> 6;
    if (lane == 0) ssum[wave] = d;
    __syncthreads();
    if (tid == 0) blocksum[b] = ssum[0] + ssum[1] + ssum[2] + ssum[3];
}

// ---------------- Kernel 3: final sum (plain store) ------------------------
__global__ __launch_bounds__(64) void chamfer_final_kernel(
    const float* __restrict__ blocksum, float* __restrict__ out)
{
    const int tid = threadIdx.x;
    float d = (tid < 36) ? blocksum[tid] : 0.f;
    #pragma unroll
    for (int off = 32; off > 0; off >>= 1) d += __shfl_down(d, off, 64);
    if (tid == 0) out[0] = d;
}

extern "C" void kernel_launch(void* const* d_in, const int* in_sizes, int n_in,
                              void* d_out, int out_size, void* d_ws, size_t ws_size,
                              hipStream_t stream) {
    const float2* pts  = (const float2*)d_in[0];            // circle 0 (offset 0)
    const float2* refs = ((const float2*)d_in[1]) + M_REF;  // last (=2nd) skeleton slice

    unsigned int* rowmin = (unsigned int*)d_ws;             // [4096]
    unsigned int* colmin = rowmin + N_PTS;                  // [32768] (contiguous)
    float* blocksum = (float*)(rowmin + N_MIN);             // [36]
    float* out = (float*)d_out;

    chamfer_init_kernel   <<<N_MIN / 1024, 256, 0, stream>>>((uint4*)rowmin);
    chamfer_main_kernel   <<<512, 256, 0, stream>>>(pts, refs, rowmin, colmin);
    chamfer_sqrtsum_kernel<<<N_MIN / 1024, 256, 0, stream>>>((const uint4*)rowmin, blocksum);
    chamfer_final_kernel  <<<1, 64, 0, stream>>>(blocksum, out);
}

// Round 8
// 33.440 us; speedup vs baseline: 5.7408x; 5.7408x over previous
//
#include <hip/hip_runtime.h>

// Chamfer distance, deterministic, no atomics, no memsets.
// pts = img_render_points[0]      : 4096 x 2 f32 (slice 0)
// refs = ref_catheter_skeleton[1] : 32768 x 2 f32 (last slice; flip is neutral)
//
// ||p-r||^2 = ||p||^2 + (||r||^2 - 2 p.r)
// Main: LDS record (-2rx,-2ry,||r||^2,0), 16 own pts/thread -> 16 pairs per
//       broadcast ds_read_b128, 2 FMA/pair + amortized v_min3. Partials
//       written exactly once (no init).
// Fold: 2-stage, vectorized, coalesced (round-4's single-stage fold was
//       latency-bound at 43 us: 144 blocks x 256 dependent strided loads).

constexpr int N_PTS = 4096;
constexpr int M_REF = 32768;
constexpr int P_OWN = 16;    // own points per thread (main)
constexpr int S_STG = 128;   // staged points per block (main)
constexpr int R_SLC = 256;   // row slices   = M_REF / S_STG
constexpr int C_SLC = 32;    // col slices   = N_PTS / S_STG
constexpr int R_GRP = 32;    // row groups after foldA (8 slices each)
constexpr int C_GRP = 4;     // col groups after foldA (8 slices each)

// ---------------- Kernel 1: pairwise partial mins --------------------------
// Grid: 512 blocks x 256 threads.
//  rows (b < 256):  own = all 4096 pts (256 thr x 16), staged = refs slice b
//  cols (b >= 256): own = refs chunk (bb&7)*4096 + ..., staged = pts slice (bb>>3)
__global__ __launch_bounds__(256) void chamfer_main_kernel(
    const float2* __restrict__ pts, const float2* __restrict__ refs,
    float* __restrict__ rowpart,   // [R_SLC][N_PTS]
    float* __restrict__ colpart)   // [C_SLC][M_REF]
{
    __shared__ float4 sh[S_STG];   // 2 KB
    const int tid = threadIdx.x, b = blockIdx.x;

    const float2* own; const float2* oth; float* part;
    int ownBase, sbase;
    if (b < 256) {                        // rows: own = pts, staged = refs
        own = pts;  oth = refs;
        ownBase = tid * P_OWN;
        sbase   = b * S_STG;
        part    = rowpart + b * N_PTS + ownBase;
    } else {                              // cols: own = refs, staged = pts
        const int bb = b - 256;
        own = refs; oth = pts;
        ownBase = (bb & 7) * 4096 + tid * P_OWN;
        sbase   = (bb >> 3) * S_STG;
        part    = colpart + (bb >> 3) * M_REF + ownBase;
    }

    if (tid < S_STG) {
        const float2 r = oth[sbase + tid];
        sh[tid] = make_float4(-2.f * r.x, -2.f * r.y, fmaf(r.x, r.x, r.y * r.y), 0.f);
    }

    float px[P_OWN], py[P_OWN], mn[P_OWN];
    {
        const float4* o4 = (const float4*)(own + ownBase);
        #pragma unroll
        for (int q = 0; q < P_OWN / 2; ++q) {
            const float4 o = o4[q];
            px[2 * q]     = o.x; py[2 * q]     = o.y;
            px[2 * q + 1] = o.z; py[2 * q + 1] = o.w;
        }
        #pragma unroll
        for (int k = 0; k < P_OWN; ++k) mn[k] = 3.0e38f;
    }
    __syncthreads();

    for (int j = 0; j < S_STG; j += 4) {   // broadcast ds_read_b128 x4 per iter
        const float4 r0 = sh[j];
        const float4 r1 = sh[j + 1];
        const float4 r2 = sh[j + 2];
        const float4 r3 = sh[j + 3];
        #pragma unroll
        for (int k = 0; k < P_OWN; ++k) {
            const float d0 = fmaf(px[k], r0.x, fmaf(py[k], r0.y, r0.z));
            const float d1 = fmaf(px[k], r1.x, fmaf(py[k], r1.y, r1.z));
            const float d2 = fmaf(px[k], r2.x, fmaf(py[k], r2.y, r2.z));
            const float d3 = fmaf(px[k], r3.x, fmaf(py[k], r3.y, r3.z));
            mn[k] = fminf(fminf(mn[k], d0), d1);   // v_min3_f32
            mn[k] = fminf(fminf(mn[k], d2), d3);   // v_min3_f32
        }
    }

    // 64 B contiguous per thread, written exactly once.
    float4* w = (float4*)part;
    #pragma unroll
    for (int q = 0; q < P_OWN / 4; ++q)
        w[q] = make_float4(mn[4 * q], mn[4 * q + 1], mn[4 * q + 2], mn[4 * q + 3]);
}

// ---------------- Kernel 2: foldA — 8-way slice reduce, float4 -------------
// 256 blocks: b<128 rows (32 groups x 4 pt-blocks of 1024 floats->256 f4),
//             b>=128 cols (4 groups x 32 pt-blocks).
__global__ __launch_bounds__(256) void chamfer_foldA_kernel(
    const float4* __restrict__ rowpart4,   // [R_SLC][N_PTS/4]
    const float4* __restrict__ colpart4,   // [C_SLC][M_REF/4]
    float4* __restrict__ rowg4,            // [R_GRP][N_PTS/4]
    float4* __restrict__ colg4)            // [C_GRP][M_REF/4]
{
    const int tid = threadIdx.x, b = blockIdx.x;
    if (b < 128) {
        const int g = b >> 2, f4 = (b & 3) * 256 + tid;      // f4 in [0,1024)
        float4 m = rowpart4[(g * 8) * (N_PTS / 4) + f4];
        #pragma unroll
        for (int j = 1; j < 8; ++j) {
            const float4 v = rowpart4[(g * 8 + j) * (N_PTS / 4) + f4];
            m.x = fminf(m.x, v.x); m.y = fminf(m.y, v.y);
            m.z = fminf(m.z, v.z); m.w = fminf(m.w, v.w);
        }
        rowg4[g * (N_PTS / 4) + f4] = m;
    } else {
        const int bb = b - 128;
        const int g = bb >> 5, f4 = (bb & 31) * 256 + tid;   // f4 in [0,8192)
        float4 m = colpart4[(g * 8) * (M_REF / 4) + f4];
        #pragma unroll
        for (int j = 1; j < 8; ++j) {
            const float4 v = colpart4[(g * 8 + j) * (M_REF / 4) + f4];
            m.x = fminf(m.x, v.x); m.y = fminf(m.y, v.y);
            m.z = fminf(m.z, v.z); m.w = fminf(m.w, v.w);
        }
        colg4[g * (M_REF / 4) + f4] = m;
    }
}

// ---------------- Kernel 3: foldB — final min, +||own||^2, sqrt, block sums
// 144 blocks x 256: blocks 0..15 -> pts (32 groups), 16..143 -> refs (4 groups)
__global__ __launch_bounds__(256) void chamfer_foldB_kernel(
    const float2* __restrict__ pts, const float2* __restrict__ refs,
    const float* __restrict__ rowg, const float* __restrict__ colg,
    float* __restrict__ blocksum)   // [144]
{
    __shared__ float ssum[4];
    const int tid = threadIdx.x, b = blockIdx.x;
    float d;
    if (b < 16) {
        const int pt = b * 256 + tid;
        float m = rowg[pt];
        #pragma unroll
        for (int g = 1; g < R_GRP; ++g) m = fminf(m, rowg[g * N_PTS + pt]);
        const float2 p = pts[pt];
        d = sqrtf(fmaxf(m + fmaf(p.x, p.x, p.y * p.y), 1e-12f));
    } else {
        const int idx = (b - 16) * 256 + tid;
        float m = colg[idx];
        #pragma unroll
        for (int g = 1; g < C_GRP; ++g) m = fminf(m, colg[g * M_REF + idx]);
        const float2 r = refs[idx];
        d = sqrtf(fmaxf(m + fmaf(r.x, r.x, r.y * r.y), 1e-12f));
    }
    #pragma unroll
    for (int off = 32; off > 0; off >>= 1) d += __shfl_down(d, off, 64);
    const int lane = tid & 63, wave = tid >> 6;
    if (lane == 0) ssum[wave] = d;
    __syncthreads();
    if (tid == 0) blocksum[b] = ssum[0] + ssum[1] + ssum[2] + ssum[3];
}

// ---------------- Kernel 4: final sum (plain store) ------------------------
__global__ __launch_bounds__(256) void chamfer_final_kernel(
    const float* __restrict__ blocksum, float* __restrict__ out)
{
    __shared__ float ssum[4];
    const int tid = threadIdx.x;
    float d = (tid < 144) ? blocksum[tid] : 0.f;
    #pragma unroll
    for (int off = 32; off > 0; off >>= 1) d += __shfl_down(d, off, 64);
    const int lane = tid & 63, wave = tid >> 6;
    if (lane == 0) ssum[wave] = d;
    __syncthreads();
    if (tid == 0) out[0] = ssum[0] + ssum[1] + ssum[2] + ssum[3];
}

extern "C" void kernel_launch(void* const* d_in, const int* in_sizes, int n_in,
                              void* d_out, int out_size, void* d_ws, size_t ws_size,
                              hipStream_t stream) {
    const float2* pts  = (const float2*)d_in[0];            // circle 0 (offset 0)
    const float2* refs = ((const float2*)d_in[1]) + M_REF;  // last (=2nd) skeleton slice

    float* rowpart  = (float*)d_ws;                         // 256*4096  = 4 MB
    float* colpart  = rowpart + R_SLC * N_PTS;              //  32*32768 = 4 MB
    float* rowg     = colpart + C_SLC * M_REF;              //  32*4096  = 512 KB
    float* colg     = rowg + R_GRP * N_PTS;                 //   4*32768 = 512 KB
    float* blocksum = colg + C_GRP * M_REF;                 // 144 f32
    float* out = (float*)d_out;

    chamfer_main_kernel <<<512, 256, 0, stream>>>(pts, refs, rowpart, colpart);
    chamfer_foldA_kernel<<<256, 256, 0, stream>>>((const float4*)rowpart,
                                                  (const float4*)colpart,
                                                  (float4*)rowg, (float4*)colg);
    chamfer_foldB_kernel<<<144, 256, 0, stream>>>(pts, refs, rowg, colg, blocksum);
    chamfer_final_kernel<<<1, 256, 0, stream>>>(blocksum, out);
}